// Round 8
// baseline (496.652 us; speedup 1.0000x reference)
//
#include <hip/hip_runtime.h>

#define B_  2
#define S_  2048
#define D_  2048
#define H_  16
#define HD_ 128

typedef __bf16 bf16;
typedef __bf16 bf16x4 __attribute__((ext_vector_type(4)));
typedef __bf16 bf16x8 __attribute__((ext_vector_type(8)));
typedef float  f32x4  __attribute__((ext_vector_type(4)));

// async global->LDS 16B copy: lds dst = wave-uniform base + lane*16
__device__ __forceinline__ void gld_lds16(const void* g, void* l) {
    __builtin_amdgcn_global_load_lds(
        (const __attribute__((address_space(1))) unsigned int*)g,
        (__attribute__((address_space(3))) unsigned int*)l, 16, 0, 0);
}

// ---------------- precast: x f32 -> hi/lo bf16 planes ----------------
__global__ __launch_bounds__(256)
void precast_kernel(const float* __restrict__ x, bf16* __restrict__ xh,
                    bf16* __restrict__ xl) {
    int i = (blockIdx.x * 256 + threadIdx.x) * 8;
    float4 a = *(const float4*)(x + i);
    float4 b = *(const float4*)(x + i + 4);
    float av[8] = {a.x, a.y, a.z, a.w, b.x, b.y, b.z, b.w};
    bf16x8 h8, l8;
#pragma unroll
    for (int e = 0; e < 8; e++) {
        bf16 hv = (bf16)av[e];
        h8[e] = hv;
        l8[e] = (bf16)(av[e] - (float)hv);
    }
    *(bf16x8*)(xh + i) = h8;
    *(bf16x8*)(xl + i) = l8;
}

// ---------------- V transpose: [bh][s][d] -> [bh][d][s], LDS-tiled ----------------
__global__ __launch_bounds__(256)
void transpose_v(const bf16* __restrict__ vp, bf16* __restrict__ vt) {
    const int bh = blockIdx.x >> 5;
    const int s0 = (blockIdx.x & 31) * 64;
    const int t = threadIdx.x;
    __shared__ bf16 tile[128 * 72];
    const bf16* src = vp + (size_t)bh * S_ * HD_;
    bf16* dst = vt + (size_t)bh * HD_ * S_;
    {
        int r = t >> 2;
        int g = (t & 3) * 4;
#pragma unroll
        for (int w = 0; w < 4; w++) {
            bf16x8 v8 = *(const bf16x8*)&src[(size_t)(s0 + r) * HD_ + (g + w) * 8];
#pragma unroll
            for (int e = 0; e < 8; e++) tile[((g + w) * 8 + e) * 72 + r] = v8[e];
        }
    }
    __syncthreads();
    {
        int d = t >> 1;
        int sg0 = (t & 1) * 4;
#pragma unroll
        for (int w = 0; w < 4; w++) {
            int sg = sg0 + w;
            *(bf16x8*)&dst[(size_t)d * S_ + s0 + sg * 8] =
                *(const bf16x8*)&tile[d * 72 + sg * 8];
        }
    }
}

// =================== GEMM: C[m,n] = sum_k A[m,k]*W[n,k] ===================
#define BK 64

template<int MODE>
__global__ __launch_bounds__(256, 3)
void gemm_nt(const bf16* __restrict__ Ah_g, const bf16* __restrict__ Al_g,
             const float* __restrict__ B0, const float* __restrict__ B1,
             const float* __restrict__ B2,
             const float* __restrict__ swp, const float* __restrict__ hm,
             bf16* __restrict__ qh_, bf16* __restrict__ ql_,
             bf16* __restrict__ kh_, bf16* __restrict__ kl_,
             bf16* __restrict__ vp_, float* __restrict__ Cf) {
    const int K = D_;
    __shared__ bf16 Ah[128 * 64];
    __shared__ bf16 Al[128 * 64];
    __shared__ bf16 Bs[128 * 64];
    const int t = threadIdx.x;
    const int wave = t >> 6, lane = t & 63;
    const int wr = wave >> 1, wc = wave & 1;
    const int m0 = blockIdx.y * 128, n0 = blockIdx.x * 128;
    const int lrow = lane & 15, lquad = lane >> 4;
    const float sw = swp[0];

    const int which = (MODE == 0) ? (n0 >> 11) : 0;
    const bool split = (MODE == 0) && (which < 2);

    const float* Bp;
    if (MODE == 0) {
        Bp = (which == 0) ? B0 : ((which == 1) ? B1 : B2);
        Bp += (size_t)(n0 & (D_ - 1)) * K;
    } else {
        Bp = B0 + (size_t)n0 * K;
    }

    const int srow8 = lane >> 3;
    const int sgrp  = lane & 7;
    const int g0 = (lquad)     ^ (lrow & 7);
    const int g1 = (lquad + 4) ^ (lrow & 7);

    f32x4 acc[4][4];
#pragma unroll
    for (int i = 0; i < 4; i++)
#pragma unroll
        for (int j = 0; j < 4; j++) acc[i][j] = (f32x4){0.f, 0.f, 0.f, 0.f};

    for (int k0 = 0; k0 < K; k0 += BK) {
#pragma unroll
        for (int p = 0; p < 4; p++) {
            int r = wave * 32 + p * 8 + srow8;
            int gcol = (sgrp ^ (r & 7)) * 8;
            gld_lds16(Ah_g + (size_t)(m0 + r) * K + k0 + gcol,
                      &Ah[(wave * 32 + p * 8) * 64]);
            if (split)
                gld_lds16(Al_g + (size_t)(m0 + r) * K + k0 + gcol,
                          &Al[(wave * 32 + p * 8) * 64]);
        }
#pragma unroll
        for (int p = 0; p < 4; p++) {
            int r = p * 32 + (t >> 3);
            int gcol = (sgrp ^ (r & 7)) * 8;
            const float* bp = Bp + (size_t)r * K + k0 + gcol;
            float4 blo = *(const float4*)bp;
            float4 bhi = *(const float4*)(bp + 4);
            bf16x8 b8;
            b8[0] = (bf16)(blo.x * sw); b8[1] = (bf16)(blo.y * sw);
            b8[2] = (bf16)(blo.z * sw); b8[3] = (bf16)(blo.w * sw);
            b8[4] = (bf16)(bhi.x * sw); b8[5] = (bf16)(bhi.y * sw);
            b8[6] = (bf16)(bhi.z * sw); b8[7] = (bf16)(bhi.w * sw);
            *(bf16x8*)&Bs[r * 64 + sgrp * 8] = b8;
        }
        __syncthreads();

#pragma unroll
        for (int kk = 0; kk < 2; kk++) {
            const int gA = kk ? g1 : g0;
            bf16x8 afh[4], afl[4], bfr[4];
#pragma unroll
            for (int i = 0; i < 4; i++) {
                int row = wr * 64 + i * 16 + lrow;
                afh[i] = *(const bf16x8*)&Ah[row * 64 + gA * 8];
                if (split) afl[i] = *(const bf16x8*)&Al[row * 64 + gA * 8];
            }
#pragma unroll
            for (int j = 0; j < 4; j++) {
                int row = wc * 64 + j * 16 + lrow;
                bfr[j] = *(const bf16x8*)&Bs[row * 64 + gA * 8];
            }
#pragma unroll
            for (int i = 0; i < 4; i++)
#pragma unroll
                for (int j = 0; j < 4; j++) {
                    acc[i][j] = __builtin_amdgcn_mfma_f32_16x16x32_bf16(
                        afh[i], bfr[j], acc[i][j], 0, 0, 0);
                    if (split)
                        acc[i][j] = __builtin_amdgcn_mfma_f32_16x16x32_bf16(
                            afl[i], bfr[j], acc[i][j], 0, 0, 0);
                }
        }
        __syncthreads();
    }

#pragma unroll
    for (int i = 0; i < 4; i++) {
#pragma unroll
        for (int j = 0; j < 4; j++) {
#pragma unroll
            for (int r = 0; r < 4; r++) {
                int m = m0 + wr * 64 + i * 16 + lquad * 4 + r;
                int n = n0 + wc * 64 + j * 16 + lrow;
                float v = acc[i][j][r];
                if (MODE == 0) {
                    int e = n & (D_ - 1);
                    int h = e >> 7, hd = e & (HD_ - 1);
                    int b = m >> 11, s = m & (S_ - 1);
                    v *= hm[h];
                    size_t idx = (((size_t)b * H_ + h) * S_ + s) * HD_ + hd;
                    if (which == 2) {
                        vp_[idx] = (bf16)v;
                    } else {
                        bf16 hv = (bf16)v;
                        bf16 lv = (bf16)(v - (float)hv);
                        if (which == 0) { qh_[idx] = hv; ql_[idx] = lv; }
                        else            { kh_[idx] = hv; kl_[idx] = lv; }
                    }
                } else {
                    Cf[(size_t)m * D_ + n] = v;
                }
            }
        }
    }
}

// =================== causal flash attention v3 ===================
// 1024 blocks, 64 q-rows/block, wave = 16 rows (Q hi/lo frags in registers).
// Chunks of 32 k-rows, DOUBLE-BUFFERED async staging (global_load_lds + XOR
// swizzle): stage c+1 after the barrier, compute c, so the next barrier's
// vmcnt drain overlaps a full compute phase. l_i rides the PV MFMA via an
// all-ones B-fragment (no sum shuffles). LDS 52 KiB -> 3 blocks/CU.
__global__ __launch_bounds__(256, 3)
void attn_kernel(const bf16* __restrict__ qh_, const bf16* __restrict__ ql_,
                 const bf16* __restrict__ kh_, const bf16* __restrict__ kl_,
                 const bf16* __restrict__ vt_, const float* __restrict__ am,
                 bf16* __restrict__ outp) {
    const int bh = blockIdx.x & 31;
    const int qblk = 31 - (blockIdx.x >> 5);
    const int b = bh >> 4, h = bh & 15;
    const int i0 = qblk * 64;
    const int t = threadIdx.x, wave = t >> 6, lane = t & 63;
    const int lrow = lane & 15, quad = lane >> 4;

    __shared__ bf16 sh[26624];                 // 52 KiB total
    bf16* skh = sh;                            // [2][32*128] swizzled
    bf16* skl = sh + 8192;                     // [2][32*128]
    bf16* svt = sh + 16384;                    // [2][128*32] swizzled
    bf16* sp  = sh + 24576 + wave * 512;       // per-wave P [16][32] swizzled

    const size_t kbase = (size_t)bh * S_ * HD_;
    const size_t vbase = (size_t)bh * HD_ * S_;

    // Q fragments (hi+lo) straight to registers
    const int qrow = i0 + wave * 16 + lrow;
    bf16x8 qhf[4], qlf[4];
#pragma unroll
    for (int c = 0; c < 4; c++) {
        qhf[c] = *(const bf16x8*)&qh_[kbase + (size_t)qrow * HD_ + c * 32 + quad * 8];
        qlf[c] = *(const bf16x8*)&ql_[kbase + (size_t)qrow * HD_ + c * 32 + quad * 8];
    }

    bf16x8 ones8;
#pragma unroll
    for (int e = 0; e < 8; e++) ones8[e] = (bf16)1.0f;

    float m_i[4];
    f32x4 O[8], Ol;
#pragma unroll
    for (int r = 0; r < 4; r++) m_i[r] = -INFINITY;
#pragma unroll
    for (int n2 = 0; n2 < 8; n2++) O[n2] = (f32x4){0.f, 0.f, 0.f, 0.f};
    Ol = (f32x4){0.f, 0.f, 0.f, 0.f};

    const float scale = 0.08838834764831845f;  // 1/sqrt(128)
    const int iwmin = i0 + wave * 16;
    const int iwmax = iwmin + 15;
    const int nch = (i0 + 64) >> 5;            // chunks of 32

    // ---- stage chunk 0 into buf 0 ----
    {
#pragma unroll
        for (int p = 0; p < 2; p++) {
            int rb = wave * 8 + p * 4;
            int r  = rb + (lane >> 4);
            int gl = ((lane & 15) ^ (r & 7)) * 8;
            gld_lds16(kh_ + kbase + (size_t)r * HD_ + gl, skh + rb * 128);
            gld_lds16(kl_ + kbase + (size_t)r * HD_ + gl, skl + rb * 128);
        }
#pragma unroll
        for (int p = 0; p < 2; p++) {
            int db = wave * 32 + p * 16;
            int d  = db + (lane >> 2);
            int gl = ((lane & 3) ^ (d & 3)) * 8;
            gld_lds16(vt_ + vbase + (size_t)d * S_ + gl, svt + db * 32);
        }
    }

    for (int c = 0; c < nch; c++) {
        __syncthreads();                       // buf[c] loads complete; buf[c^1] free
        if (c + 1 < nch) {                     // stage chunk c+1 into other buffer
            const int j0s = (c + 1) * 32;
            bf16* dkh = skh + ((c + 1) & 1) * 4096;
            bf16* dkl = skl + ((c + 1) & 1) * 4096;
            bf16* dvt = svt + ((c + 1) & 1) * 4096;
#pragma unroll
            for (int p = 0; p < 2; p++) {
                int rb = wave * 8 + p * 4;
                int r  = rb + (lane >> 4);
                int gl = ((lane & 15) ^ (r & 7)) * 8;
                gld_lds16(kh_ + kbase + (size_t)(j0s + r) * HD_ + gl, dkh + rb * 128);
                gld_lds16(kl_ + kbase + (size_t)(j0s + r) * HD_ + gl, dkl + rb * 128);
            }
#pragma unroll
            for (int p = 0; p < 2; p++) {
                int db = wave * 32 + p * 16;
                int d  = db + (lane >> 2);
                int gl = ((lane & 3) ^ (d & 3)) * 8;
                gld_lds16(vt_ + vbase + (size_t)d * S_ + j0s + gl, dvt + db * 32);
            }
        }

        const int j0 = c * 32;
        if (j0 > iwmax) continue;              // wave-uniform; all hit next barrier

        const bf16* kH = skh + (c & 1) * 4096;
        const bf16* kL = skl + (c & 1) * 4096;
        const bf16* vT = svt + (c & 1) * 4096;

        float amadd0 = (1.0f - am[b * S_ + j0 + lrow])      * -10000.0f;
        float amadd1 = (1.0f - am[b * S_ + j0 + 16 + lrow]) * -10000.0f;

        // QK^T: 16 rows x 32 cols, split 3-MFMA
        f32x4 s4[2];
        s4[0] = (f32x4){0.f, 0.f, 0.f, 0.f};
        s4[1] = (f32x4){0.f, 0.f, 0.f, 0.f};
#pragma unroll
        for (int cg = 0; cg < 4; cg++) {
#pragma unroll
            for (int nt = 0; nt < 2; nt++) {
                int ka = (nt * 16 + lrow) * 128 + (((cg * 4 + quad) ^ (lrow & 7)) * 8);
                bf16x8 kb8 = *(const bf16x8*)&kH[ka];
                bf16x8 lb8 = *(const bf16x8*)&kL[ka];
                s4[nt] = __builtin_amdgcn_mfma_f32_16x16x32_bf16(qhf[cg], kb8, s4[nt], 0, 0, 0);
                s4[nt] = __builtin_amdgcn_mfma_f32_16x16x32_bf16(qhf[cg], lb8, s4[nt], 0, 0, 0);
                s4[nt] = __builtin_amdgcn_mfma_f32_16x16x32_bf16(qlf[cg], kb8, s4[nt], 0, 0, 0);
            }
        }

        const bool msk = (j0 + 31 > iwmin);
#pragma unroll
        for (int r = 0; r < 4; r++) {
            const int irow = iwmin + quad * 4 + r;
            float x0 = s4[0][r] * scale + amadd0;
            float x1 = s4[1][r] * scale + amadd1;
            if (msk) {
                if (j0 + lrow > irow)      x0 = -INFINITY;
                if (j0 + 16 + lrow > irow) x1 = -INFINITY;
            }
            float mx = fmaxf(x0, x1);
#pragma unroll
            for (int off = 1; off < 16; off <<= 1) mx = fmaxf(mx, __shfl_xor(mx, off));
            float mnew = fmaxf(m_i[r], mx);
            float alpha = __expf(m_i[r] - mnew);
            m_i[r] = mnew;
            float p0 = __expf(x0 - mnew);
            float p1 = __expf(x1 - mnew);
            Ol[r] *= alpha;
#pragma unroll
            for (int n2 = 0; n2 < 8; n2++) O[n2][r] *= alpha;
            const int rl = quad * 4 + r;
            sp[rl * 32 + (((lrow >> 3) ^ (rl & 3)) * 8) + (lrow & 7)] = (bf16)p0;
            sp[rl * 32 + ((((lrow >> 3) + 2) ^ (rl & 3)) * 8) + (lrow & 7)] = (bf16)p1;
        }
        __asm__ volatile("s_waitcnt lgkmcnt(0)" ::: "memory");   // sp per-wave

        // PV (K=32): O += P*V^T-tiles, l rides a ones-fragment
        bf16x8 pf = *(const bf16x8*)&sp[lrow * 32 + ((quad ^ (lrow & 3)) * 8)];
#pragma unroll
        for (int n2 = 0; n2 < 8; n2++) {
            bf16x8 vf8 = *(const bf16x8*)&vT[(n2 * 16 + lrow) * 32 + ((quad ^ (lrow & 3)) * 8)];
            O[n2] = __builtin_amdgcn_mfma_f32_16x16x32_bf16(pf, vf8, O[n2], 0, 0, 0);
        }
        Ol = __builtin_amdgcn_mfma_f32_16x16x32_bf16(pf, ones8, Ol, 0, 0, 0);
    }

    float inv[4];
#pragma unroll
    for (int r = 0; r < 4; r++) inv[r] = 1.0f / Ol[r];
#pragma unroll
    for (int n2 = 0; n2 < 8; n2++)
#pragma unroll
        for (int r = 0; r < 4; r++) {
            int srow = i0 + wave * 16 + quad * 4 + r;
            outp[((size_t)(b * S_ + srow)) * D_ + h * HD_ + n2 * 16 + lrow] =
                (bf16)(O[n2][r] * inv[r]);
        }
}

// =================== launch ===================
extern "C" void kernel_launch(void* const* d_in, const int* in_sizes, int n_in,
                              void* d_out, int out_size, void* d_ws, size_t ws_size,
                              hipStream_t stream) {
    const float* x  = (const float*)d_in[0];
    const float* qm = (const float*)d_in[1];
    const float* km = (const float*)d_in[2];
    const float* vm = (const float*)d_in[3];
    const float* om = (const float*)d_in[4];
    const float* hm = (const float*)d_in[5];
    const float* am = (const float*)d_in[6];
    const float* sw = (const float*)d_in[7];
    float* out = (float*)d_out;

    const size_t P = (size_t)B_ * H_ * S_ * HD_ * sizeof(bf16);   // 16777216
    char* ws = (char*)d_ws;
    bf16* xh = (bf16*)(ws + 0 * P);
    bf16* xl = (bf16*)(ws + 1 * P);
    bf16* qh = (bf16*)(ws + 2 * P);
    bf16* ql = (bf16*)(ws + 3 * P);
    bf16* kh = (bf16*)(ws + 4 * P);
    bf16* kl = (bf16*)(ws + 5 * P);
    bf16* vp = (bf16*)d_out;                    // [bh][s][d]
    bf16* vt = (bf16*)((char*)d_out + P);       // [bh][d][s]
    bf16* attn_out = (bf16*)(ws + 0 * P);

    precast_kernel<<<(B_ * S_ * D_) / (256 * 8), 256, 0, stream>>>(x, xh, xl);

    gemm_nt<0><<<dim3(48, 32), 256, 0, stream>>>(
        xh, xl, qm, km, vm, sw, hm, qh, ql, kh, kl, vp, nullptr);

    transpose_v<<<1024, 256, 0, stream>>>(vp, vt);

    attn_kernel<<<1024, 256, 0, stream>>>(qh, ql, kh, kl, vt, am, attn_out);

    gemm_nt<1><<<dim3(16, 32), 256, 0, stream>>>(
        attn_out, nullptr, om, nullptr, nullptr, sw, hm,
        nullptr, nullptr, nullptr, nullptr, nullptr, out);
}

// Round 10
// 495.750 us; speedup vs baseline: 1.0018x; 1.0018x over previous
//
#include <hip/hip_runtime.h>

#define B_  2
#define S_  2048
#define D_  2048
#define H_  16
#define HD_ 128

typedef __bf16 bf16;
typedef __bf16 bf16x4 __attribute__((ext_vector_type(4)));
typedef __bf16 bf16x8 __attribute__((ext_vector_type(8)));
typedef float  f32x4  __attribute__((ext_vector_type(4)));

// async global->LDS 16B copy: lds dst = wave-uniform base + lane*16
__device__ __forceinline__ void gld_lds16(const void* g, void* l) {
    __builtin_amdgcn_global_load_lds(
        (const __attribute__((address_space(1))) unsigned int*)g,
        (__attribute__((address_space(3))) unsigned int*)l, 16, 0, 0);
}

// ---------------- precast: x f32 -> hi/lo bf16 planes ----------------
__global__ __launch_bounds__(256)
void precast_kernel(const float* __restrict__ x, bf16* __restrict__ xh,
                    bf16* __restrict__ xl) {
    int i = (blockIdx.x * 256 + threadIdx.x) * 8;
    float4 a = *(const float4*)(x + i);
    float4 b = *(const float4*)(x + i + 4);
    float av[8] = {a.x, a.y, a.z, a.w, b.x, b.y, b.z, b.w};
    bf16x8 h8, l8;
#pragma unroll
    for (int e = 0; e < 8; e++) {
        bf16 hv = (bf16)av[e];
        h8[e] = hv;
        l8[e] = (bf16)(av[e] - (float)hv);
    }
    *(bf16x8*)(xh + i) = h8;
    *(bf16x8*)(xl + i) = l8;
}

// ---------------- V transpose: [bh][s][d] -> [bh][d][s], LDS-tiled ----------------
__global__ __launch_bounds__(256)
void transpose_v(const bf16* __restrict__ vp, bf16* __restrict__ vt) {
    const int bh = blockIdx.x >> 5;
    const int s0 = (blockIdx.x & 31) * 64;
    const int t = threadIdx.x;
    __shared__ bf16 tile[128 * 72];
    const bf16* src = vp + (size_t)bh * S_ * HD_;
    bf16* dst = vt + (size_t)bh * HD_ * S_;
    {
        int r = t >> 2;
        int g = (t & 3) * 4;
#pragma unroll
        for (int w = 0; w < 4; w++) {
            bf16x8 v8 = *(const bf16x8*)&src[(size_t)(s0 + r) * HD_ + (g + w) * 8];
#pragma unroll
            for (int e = 0; e < 8; e++) tile[((g + w) * 8 + e) * 72 + r] = v8[e];
        }
    }
    __syncthreads();
    {
        int d = t >> 1;
        int sg0 = (t & 1) * 4;
#pragma unroll
        for (int w = 0; w < 4; w++) {
            int sg = sg0 + w;
            *(bf16x8*)&dst[(size_t)d * S_ + s0 + sg * 8] =
                *(const bf16x8*)&tile[d * 72 + sg * 8];
        }
    }
}

// =================== GEMM: C[m,n] = sum_k A[m,k]*W[n,k] ===================
#define BK 64

template<int MODE>
__global__ __launch_bounds__(256, 3)
void gemm_nt(const bf16* __restrict__ Ah_g, const bf16* __restrict__ Al_g,
             const float* __restrict__ B0, const float* __restrict__ B1,
             const float* __restrict__ B2,
             const float* __restrict__ swp, const float* __restrict__ hm,
             bf16* __restrict__ qh_, bf16* __restrict__ ql_,
             bf16* __restrict__ kh_, bf16* __restrict__ kl_,
             bf16* __restrict__ vp_, float* __restrict__ Cf) {
    const int K = D_;
    __shared__ bf16 Ah[128 * 64];
    __shared__ bf16 Al[128 * 64];
    __shared__ bf16 Bs[128 * 64];
    const int t = threadIdx.x;
    const int wave = t >> 6, lane = t & 63;
    const int wr = wave >> 1, wc = wave & 1;
    const int m0 = blockIdx.y * 128, n0 = blockIdx.x * 128;
    const int lrow = lane & 15, lquad = lane >> 4;
    const float sw = swp[0];

    const int which = (MODE == 0) ? (n0 >> 11) : 0;
    const bool split = (MODE == 0) && (which < 2);

    const float* Bp;
    if (MODE == 0) {
        Bp = (which == 0) ? B0 : ((which == 1) ? B1 : B2);
        Bp += (size_t)(n0 & (D_ - 1)) * K;
    } else {
        Bp = B0 + (size_t)n0 * K;
    }

    const int srow8 = lane >> 3;
    const int sgrp  = lane & 7;
    const int g0 = (lquad)     ^ (lrow & 7);
    const int g1 = (lquad + 4) ^ (lrow & 7);

    f32x4 acc[4][4];
#pragma unroll
    for (int i = 0; i < 4; i++)
#pragma unroll
        for (int j = 0; j < 4; j++) acc[i][j] = (f32x4){0.f, 0.f, 0.f, 0.f};

    for (int k0 = 0; k0 < K; k0 += BK) {
#pragma unroll
        for (int p = 0; p < 4; p++) {
            int r = wave * 32 + p * 8 + srow8;
            int gcol = (sgrp ^ (r & 7)) * 8;
            gld_lds16(Ah_g + (size_t)(m0 + r) * K + k0 + gcol,
                      &Ah[(wave * 32 + p * 8) * 64]);
            if (split)
                gld_lds16(Al_g + (size_t)(m0 + r) * K + k0 + gcol,
                          &Al[(wave * 32 + p * 8) * 64]);
        }
#pragma unroll
        for (int p = 0; p < 4; p++) {
            int r = p * 32 + (t >> 3);
            int gcol = (sgrp ^ (r & 7)) * 8;
            const float* bp = Bp + (size_t)r * K + k0 + gcol;
            float4 blo = *(const float4*)bp;
            float4 bhi = *(const float4*)(bp + 4);
            bf16x8 b8;
            b8[0] = (bf16)(blo.x * sw); b8[1] = (bf16)(blo.y * sw);
            b8[2] = (bf16)(blo.z * sw); b8[3] = (bf16)(blo.w * sw);
            b8[4] = (bf16)(bhi.x * sw); b8[5] = (bf16)(bhi.y * sw);
            b8[6] = (bf16)(bhi.z * sw); b8[7] = (bf16)(bhi.w * sw);
            *(bf16x8*)&Bs[r * 64 + sgrp * 8] = b8;
        }
        __syncthreads();

#pragma unroll
        for (int kk = 0; kk < 2; kk++) {
            const int gA = kk ? g1 : g0;
            bf16x8 afh[4], afl[4], bfr[4];
#pragma unroll
            for (int i = 0; i < 4; i++) {
                int row = wr * 64 + i * 16 + lrow;
                afh[i] = *(const bf16x8*)&Ah[row * 64 + gA * 8];
                if (split) afl[i] = *(const bf16x8*)&Al[row * 64 + gA * 8];
            }
#pragma unroll
            for (int j = 0; j < 4; j++) {
                int row = wc * 64 + j * 16 + lrow;
                bfr[j] = *(const bf16x8*)&Bs[row * 64 + gA * 8];
            }
#pragma unroll
            for (int i = 0; i < 4; i++)
#pragma unroll
                for (int j = 0; j < 4; j++) {
                    acc[i][j] = __builtin_amdgcn_mfma_f32_16x16x32_bf16(
                        afh[i], bfr[j], acc[i][j], 0, 0, 0);
                    if (split)
                        acc[i][j] = __builtin_amdgcn_mfma_f32_16x16x32_bf16(
                            afl[i], bfr[j], acc[i][j], 0, 0, 0);
                }
        }
        __syncthreads();
    }

#pragma unroll
    for (int i = 0; i < 4; i++) {
#pragma unroll
        for (int j = 0; j < 4; j++) {
#pragma unroll
            for (int r = 0; r < 4; r++) {
                int m = m0 + wr * 64 + i * 16 + lquad * 4 + r;
                int n = n0 + wc * 64 + j * 16 + lrow;
                float v = acc[i][j][r];
                if (MODE == 0) {
                    int e = n & (D_ - 1);
                    int h = e >> 7, hd = e & (HD_ - 1);
                    int b = m >> 11, s = m & (S_ - 1);
                    v *= hm[h];
                    size_t idx = (((size_t)b * H_ + h) * S_ + s) * HD_ + hd;
                    if (which == 2) {
                        vp_[idx] = (bf16)v;
                    } else {
                        bf16 hv = (bf16)v;
                        bf16 lv = (bf16)(v - (float)hv);
                        if (which == 0) { qh_[idx] = hv; ql_[idx] = lv; }
                        else            { kh_[idx] = hv; kl_[idx] = lv; }
                    }
                } else {
                    Cf[(size_t)m * D_ + n] = v;
                }
            }
        }
    }
}

// =================== causal flash attention v4b ===================
// 1024 blocks, 64 q-rows/block, wave = 16 rows (Q hi/lo frags in registers).
// Chunks of 64 k-rows, single LDS buffer + REGISTER prefetch. Swizzle
// convention (matches global_load_lds semantics): lane loads SOURCE group
// (lane&W)^(r&7) from global and stores at PHYSICAL group (lane&W), so phys
// group g holds source g^(r&7); frag reads apply ^(lrow&7) once. l_i rides
// the PV MFMA via an all-ones B-fragment; softmax in exp2 domain.
// LDS 57 KiB -> 2 blocks/CU.
#define SPLD 72

__global__ __launch_bounds__(256, 2)
void attn_kernel(const bf16* __restrict__ qh_, const bf16* __restrict__ ql_,
                 const bf16* __restrict__ kh_, const bf16* __restrict__ kl_,
                 const bf16* __restrict__ vt_, const float* __restrict__ am,
                 bf16* __restrict__ outp) {
    const int bh = blockIdx.x & 31;
    const int qblk = 31 - (blockIdx.x >> 5);
    const int b = bh >> 4, h = bh & 15;
    const int i0 = qblk * 64;
    const int t = threadIdx.x, wave = t >> 6, lane = t & 63;
    const int lrow = lane & 15, quad = lane >> 4;

    __shared__ bf16 skh[64 * 128];                 // swizzled [j][d]
    __shared__ bf16 skl[64 * 128];
    __shared__ bf16 svt[128 * 64];                 // swizzled [d][j]
    __shared__ bf16 sp[4][16 * SPLD];              // per-wave P strip (padded)

    const size_t kbase = (size_t)bh * S_ * HD_;
    const size_t vbase = (size_t)bh * HD_ * S_;

    // per-wave staging slices (4 b128 each for K-hi, K-lo, V^T)
    // source column swizzled; LDS store at lane-natural physical group.
    int krr[4], kcc[4], ldk[4];
#pragma unroll
    for (int p = 0; p < 4; p++) {
        int r = wave * 16 + p * 4 + (lane >> 4);
        krr[p] = r;
        kcc[p] = ((lane & 15) ^ (r & 7)) * 8;      // global source column
        ldk[p] = r * 128 + (lane & 15) * 8;        // physical LDS offset
    }
    int vdd[4], vcc[4], ldv[4];
#pragma unroll
    for (int p = 0; p < 4; p++) {
        int d = wave * 32 + p * 8 + (lane >> 3);
        vdd[p] = d;
        vcc[p] = ((lane & 7) ^ (d & 7)) * 8;       // global source column
        ldv[p] = d * 64 + (lane & 7) * 8;          // physical LDS offset
    }

    // Q fragments (hi+lo) straight to registers
    const int qrow = i0 + wave * 16 + lrow;
    bf16x8 qhf[4], qlf[4];
#pragma unroll
    for (int c = 0; c < 4; c++) {
        qhf[c] = *(const bf16x8*)&qh_[kbase + (size_t)qrow * HD_ + c * 32 + quad * 8];
        qlf[c] = *(const bf16x8*)&ql_[kbase + (size_t)qrow * HD_ + c * 32 + quad * 8];
    }

    bf16x8 ones8;
#pragma unroll
    for (int e = 0; e < 8; e++) ones8[e] = (bf16)1.0f;

    float m_i[4];
    f32x4 O[8], Ol;
#pragma unroll
    for (int r = 0; r < 4; r++) m_i[r] = -INFINITY;
#pragma unroll
    for (int n2 = 0; n2 < 8; n2++) O[n2] = (f32x4){0.f, 0.f, 0.f, 0.f};
    Ol = (f32x4){0.f, 0.f, 0.f, 0.f};

    // exp2-domain: scale2 = (1/sqrt(128))*log2(e); amadd2 = (1-am)*(-10000*log2(e))
    const float scale2 = 0.08838834764831845f * 1.44269504088896f;
    const int nch = (i0 >> 6) + 1;                 // chunks of 64

    // prefetch chunk 0 into regs
    bf16x8 pkh[4], pkl[4], pvt[4];
#pragma unroll
    for (int p = 0; p < 4; p++) {
        pkh[p] = *(const bf16x8*)&kh_[kbase + (size_t)krr[p] * HD_ + kcc[p]];
        pkl[p] = *(const bf16x8*)&kl_[kbase + (size_t)krr[p] * HD_ + kcc[p]];
        pvt[p] = *(const bf16x8*)&vt_[vbase + (size_t)vdd[p] * S_ + vcc[p]];
    }

    for (int c = 0; c < nch; c++) {
        const int j0 = c * 64;
        __syncthreads();                           // prior compute done
        // LDS <- prefetched regs (per-lane ds_write_b128, swizzled layout)
#pragma unroll
        for (int p = 0; p < 4; p++) {
            *(bf16x8*)&skh[ldk[p]] = pkh[p];
            *(bf16x8*)&skl[ldk[p]] = pkl[p];
            *(bf16x8*)&svt[ldv[p]] = pvt[p];
        }
        __syncthreads();                           // LDS visible
        if (c + 1 < nch) {                         // prefetch next chunk
            const int j0n = j0 + 64;
#pragma unroll
            for (int p = 0; p < 4; p++) {
                pkh[p] = *(const bf16x8*)&kh_[kbase + (size_t)(j0n + krr[p]) * HD_ + kcc[p]];
                pkl[p] = *(const bf16x8*)&kl_[kbase + (size_t)(j0n + krr[p]) * HD_ + kcc[p]];
                pvt[p] = *(const bf16x8*)&vt_[vbase + (size_t)vdd[p] * S_ + j0n + vcc[p]];
            }
        }

        float amadd[4];
#pragma unroll
        for (int nt = 0; nt < 4; nt++)
            amadd[nt] = (1.0f - am[b * S_ + j0 + nt * 16 + lrow]) * -14426.950408f;

        // QK^T: 16 rows x 64 cols, split 3-MFMA, swizzled B-frag reads
        f32x4 s4[4];
#pragma unroll
        for (int nt = 0; nt < 4; nt++) s4[nt] = (f32x4){0.f, 0.f, 0.f, 0.f};
#pragma unroll
        for (int cg = 0; cg < 4; cg++) {
#pragma unroll
            for (int nt = 0; nt < 4; nt++) {
                int ka = (nt * 16 + lrow) * 128 + (((cg * 4 + quad) ^ (lrow & 7)) * 8);
                bf16x8 kb8 = *(const bf16x8*)&skh[ka];
                bf16x8 lb8 = *(const bf16x8*)&skl[ka];
                s4[nt] = __builtin_amdgcn_mfma_f32_16x16x32_bf16(qhf[cg], kb8, s4[nt], 0, 0, 0);
                s4[nt] = __builtin_amdgcn_mfma_f32_16x16x32_bf16(qhf[cg], lb8, s4[nt], 0, 0, 0);
                s4[nt] = __builtin_amdgcn_mfma_f32_16x16x32_bf16(qlf[cg], kb8, s4[nt], 0, 0, 0);
            }
        }

        const bool diag = (j0 == i0);
#pragma unroll
        for (int r = 0; r < 4; r++) {
            const int rrow = wave * 16 + quad * 4 + r;
            float sv[4];
            float mx = -INFINITY;
#pragma unroll
            for (int nt = 0; nt < 4; nt++) {
                float xv = s4[nt][r] * scale2 + amadd[nt];
                if (diag && (nt * 16 + lrow) > rrow) xv = -INFINITY;
                sv[nt] = xv;
                mx = fmaxf(mx, xv);
            }
#pragma unroll
            for (int off = 1; off < 16; off <<= 1) mx = fmaxf(mx, __shfl_xor(mx, off));
            float mnew = fmaxf(m_i[r], mx);
            float alpha = exp2f(m_i[r] - mnew);
            m_i[r] = mnew;
            Ol[r] *= alpha;
#pragma unroll
            for (int n2 = 0; n2 < 8; n2++) O[n2][r] *= alpha;
#pragma unroll
            for (int nt = 0; nt < 4; nt++)
                sp[wave][(quad * 4 + r) * SPLD + nt * 16 + lrow] = (bf16)exp2f(sv[nt] - mnew);
        }
        __asm__ volatile("s_waitcnt lgkmcnt(0)" ::: "memory");   // sp per-wave

        // PV: O += P * V, l rides the ones-fragment; swizzled V^T frag reads
#pragma unroll
        for (int k2 = 0; k2 < 2; k2++) {
            bf16x8 pf = *(const bf16x8*)&sp[wave][lrow * SPLD + k2 * 32 + quad * 8];
            const int gp = ((quad + k2 * 4) ^ (lrow & 7)) * 8;
#pragma unroll
            for (int n2 = 0; n2 < 8; n2++) {
                bf16x8 vf8 = *(const bf16x8*)&svt[(n2 * 16 + lrow) * 64 + gp];
                O[n2] = __builtin_amdgcn_mfma_f32_16x16x32_bf16(pf, vf8, O[n2], 0, 0, 0);
            }
            Ol = __builtin_amdgcn_mfma_f32_16x16x32_bf16(pf, ones8, Ol, 0, 0, 0);
        }
    }

    float inv[4];
#pragma unroll
    for (int r = 0; r < 4; r++) inv[r] = 1.0f / Ol[r];
#pragma unroll
    for (int n2 = 0; n2 < 8; n2++)
#pragma unroll
        for (int r = 0; r < 4; r++) {
            int srow = i0 + wave * 16 + quad * 4 + r;
            outp[((size_t)(b * S_ + srow)) * D_ + h * HD_ + n2 * 16 + lrow] =
                (bf16)(O[n2][r] * inv[r]);
        }
}

// =================== launch ===================
extern "C" void kernel_launch(void* const* d_in, const int* in_sizes, int n_in,
                              void* d_out, int out_size, void* d_ws, size_t ws_size,
                              hipStream_t stream) {
    const float* x  = (const float*)d_in[0];
    const float* qm = (const float*)d_in[1];
    const float* km = (const float*)d_in[2];
    const float* vm = (const float*)d_in[3];
    const float* om = (const float*)d_in[4];
    const float* hm = (const float*)d_in[5];
    const float* am = (const float*)d_in[6];
    const float* sw = (const float*)d_in[7];
    float* out = (float*)d_out;

    const size_t P = (size_t)B_ * H_ * S_ * HD_ * sizeof(bf16);   // 16777216
    char* ws = (char*)d_ws;
    bf16* xh = (bf16*)(ws + 0 * P);
    bf16* xl = (bf16*)(ws + 1 * P);
    bf16* qh = (bf16*)(ws + 2 * P);
    bf16* ql = (bf16*)(ws + 3 * P);
    bf16* kh = (bf16*)(ws + 4 * P);
    bf16* kl = (bf16*)(ws + 5 * P);
    bf16* vp = (bf16*)d_out;                    // [bh][s][d]
    bf16* vt = (bf16*)((char*)d_out + P);       // [bh][d][s]
    bf16* attn_out = (bf16*)(ws + 0 * P);

    precast_kernel<<<(B_ * S_ * D_) / (256 * 8), 256, 0, stream>>>(x, xh, xl);

    gemm_nt<0><<<dim3(48, 32), 256, 0, stream>>>(
        xh, xl, qm, km, vm, sw, hm, qh, ql, kh, kl, vp, nullptr);

    transpose_v<<<1024, 256, 0, stream>>>(vp, vt);

    attn_kernel<<<1024, 256, 0, stream>>>(qh, ql, kh, kl, vt, am, attn_out);

    gemm_nt<1><<<dim3(16, 32), 256, 0, stream>>>(
        attn_out, nullptr, om, nullptr, nullptr, sw, hm,
        nullptr, nullptr, nullptr, nullptr, nullptr, out);
}